// Round 1
// baseline (272.508 us; speedup 1.0000x reference)
//
#include <hip/hip_runtime.h>
#include <math.h>

// Problem constants (from reference): x is (4, 8192, 1024) f32.
// _mod_step is an exact identity (processed == routed => new_vals == routed),
// so states[0..2] == x up to ~1ulp. ACT combine then reduces to:
//   h = sigmoid(x . halt_w + halt_b); 3-step scalar recurrence -> (P, n)
//   out = P * x ; ponder = 0.01 * mean(n)
#define N_TOKENS 32768   // 4 * 8192
#define DIM      1024
#define WAVES_PER_BLOCK 4

__global__ void modgpt_init(int* __restrict__ n_acc) {
    if (threadIdx.x == 0 && blockIdx.x == 0) n_acc[0] = 0;
}

__global__ __launch_bounds__(256) void modgpt_main(
        const float* __restrict__ x,
        const float* __restrict__ halt_w,
        const float* __restrict__ halt_b,
        float* __restrict__ out,
        int* __restrict__ n_acc) {
    const int wave = threadIdx.x >> 6;
    const int lane = threadIdx.x & 63;
    const int token = blockIdx.x * WAVES_PER_BLOCK + wave;

    const float4* __restrict__ xin = (const float4*)(x + (size_t)token * DIM);
    const float4* __restrict__ w4  = (const float4*)halt_w;

    // Each lane: 4 float4 = 16 elements; stride 64 float4 between accesses
    // -> each instruction is a fully coalesced 1 KiB wave access.
    float4 v0 = xin[lane];
    float4 v1 = xin[lane + 64];
    float4 v2 = xin[lane + 128];
    float4 v3 = xin[lane + 192];
    float4 w0 = w4[lane];
    float4 w1 = w4[lane + 64];
    float4 w2 = w4[lane + 128];
    float4 w3 = w4[lane + 192];

    float dot = v0.x * w0.x + v0.y * w0.y + v0.z * w0.z + v0.w * w0.w
              + v1.x * w1.x + v1.y * w1.y + v1.z * w1.z + v1.w * w1.w
              + v2.x * w2.x + v2.y * w2.y + v2.z * w2.z + v2.w * w2.w
              + v3.x * w3.x + v3.y * w3.y + v3.z * w3.z + v3.w * w3.w;

    // wave-64 butterfly reduction
    #pragma unroll
    for (int off = 32; off >= 1; off >>= 1)
        dot += __shfl_xor(dot, off, 64);

    const float h = 1.0f / (1.0f + expf(-(dot + halt_b[0])));

    // Exact ACT recurrence (EPS = 0.01): still = acc < 0.99; use_rem = (acc+h) > 0.99
    float acc = 0.0f, rem = 1.0f, P = 0.0f;
    int n = 0;
    #pragma unroll
    for (int s = 0; s < 3; ++s) {
        if (acc < 0.99f) {
            const float na = acc + h;
            const float p  = (na > 0.99f) ? rem : h;
            P   += p;
            acc += p;
            rem -= p;
            n   += 1;
        }
    }

    float4* __restrict__ o = (float4*)(out + (size_t)token * DIM);
    v0.x *= P; v0.y *= P; v0.z *= P; v0.w *= P;
    v1.x *= P; v1.y *= P; v1.z *= P; v1.w *= P;
    v2.x *= P; v2.y *= P; v2.z *= P; v2.w *= P;
    v3.x *= P; v3.y *= P; v3.z *= P; v3.w *= P;
    o[lane]       = v0;
    o[lane + 64]  = v1;
    o[lane + 128] = v2;
    o[lane + 192] = v3;

    // per-block n reduction -> one device-scope atomic per block
    __shared__ int sn[WAVES_PER_BLOCK];
    if (lane == 0) sn[wave] = n;
    __syncthreads();
    if (threadIdx.x == 0)
        atomicAdd(n_acc, sn[0] + sn[1] + sn[2] + sn[3]);
}

__global__ void modgpt_finalize(const int* __restrict__ n_acc,
                                float* __restrict__ ponder_out) {
    if (threadIdx.x == 0 && blockIdx.x == 0)
        ponder_out[0] = 0.01f * ((float)n_acc[0] / (float)N_TOKENS);
}

extern "C" void kernel_launch(void* const* d_in, const int* in_sizes, int n_in,
                              void* d_out, int out_size, void* d_ws, size_t ws_size,
                              hipStream_t stream) {
    const float* x        = (const float*)d_in[0];
    // d_in[1] = router_w : mathematically unused (mod step is identity)
    const float* halt_w   = (const float*)d_in[2];
    const float* halt_b   = (const float*)d_in[3];
    float* out            = (float*)d_out;               // 33554432 elems + 1 scalar
    int*   n_acc          = (int*)d_ws;

    modgpt_init<<<1, 64, 0, stream>>>(n_acc);
    modgpt_main<<<N_TOKENS / WAVES_PER_BLOCK, 256, 0, stream>>>(
        x, halt_w, halt_b, out, n_acc);
    modgpt_finalize<<<1, 64, 0, stream>>>(n_acc, out + (size_t)N_TOKENS * DIM);
}

// Round 2
// 241.743 us; speedup vs baseline: 1.1273x; 1.1273x over previous
//
#include <hip/hip_runtime.h>
#include <math.h>

// x: (4, 8192, 1024) f32. _mod_step is an exact identity, so the whole problem
// reduces to: h = sigmoid(x·halt_w + halt_b) per token; 3-step ACT recurrence
// -> (P, n); out = P*x; ponder = 0.01*mean(n).
#define N_TOKENS 32768   // 4 * 8192
#define DIM      1024
#define WAVES_PER_BLOCK 4
#define TOK_PER_WAVE 8   // 8192/(4*8) = 1024 blocks -> 8x fewer atomics

typedef float v4f __attribute__((ext_vector_type(4)));

__global__ void modgpt_init(int* __restrict__ n_acc) {
    if (threadIdx.x == 0 && blockIdx.x == 0) n_acc[0] = 0;
}

__global__ __launch_bounds__(256) void modgpt_main(
        const float* __restrict__ x,
        const float* __restrict__ halt_w,
        const float* __restrict__ halt_b,
        float* __restrict__ out,
        int* __restrict__ n_acc) {
    const int wave = threadIdx.x >> 6;
    const int lane = threadIdx.x & 63;
    const int token0 = (blockIdx.x * WAVES_PER_BLOCK + wave) * TOK_PER_WAVE;

    const v4f* __restrict__ xin = (const v4f*)(x + (size_t)token0 * DIM);
    v4f* __restrict__ oout      = (v4f*)(out + (size_t)token0 * DIM);
    const v4f* __restrict__ w4  = (const v4f*)halt_w;

    // halt weights: resident in registers for all 8 tokens (L1-hot anyway)
    const v4f w0 = w4[lane];
    const v4f w1 = w4[lane + 64];
    const v4f w2 = w4[lane + 128];
    const v4f w3 = w4[lane + 192];
    const float hb = halt_b[0];

    int n_sum = 0;

    // software pipeline: token t's reduce chain overlaps token t+1's loads
    v4f c0 = xin[lane];
    v4f c1 = xin[lane + 64];
    v4f c2 = xin[lane + 128];
    v4f c3 = xin[lane + 192];

    #pragma unroll
    for (int t = 0; t < TOK_PER_WAVE; ++t) {
        v4f p0, p1, p2, p3;
        if (t + 1 < TOK_PER_WAVE) {
            const v4f* nx = xin + (size_t)(t + 1) * 256;
            p0 = nx[lane];
            p1 = nx[lane + 64];
            p2 = nx[lane + 128];
            p3 = nx[lane + 192];
        }

        // per-lane partial dot (16 elements), then wave-64 butterfly
        v4f m = c0 * w0 + c1 * w1 + c2 * w2 + c3 * w3;
        float dot = m.x + m.y + m.z + m.w;
        #pragma unroll
        for (int off = 32; off >= 1; off >>= 1)
            dot += __shfl_xor(dot, off, 64);

        const float h = 1.0f / (1.0f + expf(-(dot + hb)));

        // exact ACT recurrence (EPS = 0.01)
        float acc = 0.0f, rem = 1.0f, P = 0.0f;
        int n = 0;
        #pragma unroll
        for (int s = 0; s < 3; ++s) {
            if (acc < 0.99f) {
                const float na = acc + h;
                const float p  = (na > 0.99f) ? rem : h;
                P   += p;
                acc += p;
                rem -= p;
                n   += 1;
            }
        }
        n_sum += n;

        // nontemporal stores: out is write-once, keep x resident in L2/LLC
        v4f* op = oout + (size_t)t * 256;
        __builtin_nontemporal_store(c0 * P, op + lane);
        __builtin_nontemporal_store(c1 * P, op + lane + 64);
        __builtin_nontemporal_store(c2 * P, op + lane + 128);
        __builtin_nontemporal_store(c3 * P, op + lane + 192);

        c0 = p0; c1 = p1; c2 = p2; c3 = p3;
    }

    // per-block n reduction -> one atomic per block (1024 total)
    __shared__ int sn[WAVES_PER_BLOCK];
    if (lane == 0) sn[wave] = n_sum;
    __syncthreads();
    if (threadIdx.x == 0)
        atomicAdd(n_acc, sn[0] + sn[1] + sn[2] + sn[3]);
}

__global__ void modgpt_finalize(const int* __restrict__ n_acc,
                                float* __restrict__ ponder_out) {
    if (threadIdx.x == 0 && blockIdx.x == 0)
        ponder_out[0] = 0.01f * ((float)n_acc[0] / (float)N_TOKENS);
}

extern "C" void kernel_launch(void* const* d_in, const int* in_sizes, int n_in,
                              void* d_out, int out_size, void* d_ws, size_t ws_size,
                              hipStream_t stream) {
    const float* x        = (const float*)d_in[0];
    // d_in[1] = router_w : mathematically unused (mod step is identity)
    const float* halt_w   = (const float*)d_in[2];
    const float* halt_b   = (const float*)d_in[3];
    float* out            = (float*)d_out;
    int*   n_acc          = (int*)d_ws;

    modgpt_init<<<1, 64, 0, stream>>>(n_acc);
    modgpt_main<<<N_TOKENS / (WAVES_PER_BLOCK * TOK_PER_WAVE), 256, 0, stream>>>(
        x, halt_w, halt_b, out, n_acc);
    modgpt_finalize<<<1, 64, 0, stream>>>(n_acc, out + (size_t)N_TOKENS * DIM);
}